// Round 18
// baseline (641.060 us; speedup 1.0000x reference)
//
#include <hip/hip_runtime.h>
#include <hip/hip_bf16.h>
#include <stdint.h>

#define IN_SZ 128
#define HID 128
#define OUT_SZ 67
#define SEQ 512
#define BATCH 2048
#define BT 8
#define NTHR 384   // waves 0..3 compute (H-half + i2o), 4..5 service (x + X-half)
#define SB (SEQ * BATCH)   // 1048576

typedef __attribute__((ext_vector_type(4))) float f32x4;
typedef __attribute__((ext_vector_type(8))) short s16x8;
typedef __attribute__((ext_vector_type(8))) __bf16 bf16x8;

static __device__ __forceinline__ unsigned short f2bf(float f) {
  union { float f; uint32_t u; } c; c.f = f;
  uint32_t u = c.u;
  uint32_t r = u + 0x7FFFu + ((u >> 16) & 1u);
  return (unsigned short)(r >> 16);
}
static __device__ __forceinline__ uint32_t pk2bf(float lo, float hi) {
  __hip_bfloat162 h2 = __float22bfloat162_rn(float2{lo, hi});
  union { __hip_bfloat162 h; uint32_t u; } c; c.h = h2;
  return c.u;
}
static __device__ __forceinline__ float fast_tanh(float x) {
  float e = __builtin_amdgcn_exp2f(x * 2.885390081777927f);
  float r = __builtin_amdgcn_rcpf(e + 1.f);
  return __builtin_fmaf(-2.f, r, 1.f);
}
static __device__ __forceinline__ void mfma16(f32x4& c, s16x8 a, s16x8 b) {
  c = __builtin_amdgcn_mfma_f32_16x16x32_bf16(
        __builtin_bit_cast(bf16x8, a), __builtin_bit_cast(bf16x8, b), c, 0, 0, 0);
}
#define KOFF(g, j) (4 * (g) + ((j) & 3) + (((j) >> 2) << 4))

// clobber-free barrier (validated R9-R17): lgkm-only drain, vm ops float across
static __device__ __forceinline__ void frag_barrier() {
  __builtin_amdgcn_sched_barrier(0);
  asm volatile("s_waitcnt lgkmcnt(0)");
  __builtin_amdgcn_s_barrier();
  __builtin_amdgcn_sched_barrier(0);
}

__global__ __launch_bounds__(NTHR, 1) void rnn_kernel(
    const float* __restrict__ x, const float* __restrict__ hidden,
    const float* __restrict__ mask, const float* __restrict__ Wi2h,
    const float* __restrict__ bi2h, const float* __restrict__ Wi2o,
    const float* __restrict__ bi2o, float* __restrict__ Y) {

  __shared__ s16x8 sH[2][4][64];   // h frags, double buffer; 8 KB
  __shared__ f32x4 sA[2][8][64];   // ax = bi2h + Wx*x_t partials (D-frag layout); 16 KB

  const int tid = threadIdx.x;
  const int wave = tid >> 6;      // 0..3 compute (tiles 2w,2w+1), 4..5 service
  const int lane = tid & 63;
  const int g = lane >> 4;
  const int n16 = lane & 15;
  const int bid = ((blockIdx.x & 7) << 5) | (blockIdx.x >> 3);  // XCD swizzle
  const int b0 = bid * BT;
  const int cc = (b0 + n16 < BATCH) ? (b0 + n16) : (BATCH - 1);  // clamped col

  if (wave < 4) {
    // ====== COMPUTE: H-half of i2h + tanh + i2o + stores; no global loads ======
    // W_H[tl][kk] = A-frag of Wi2h tile (2w+tl), k-tile 4+kk (the h columns)
    s16x8 WH0[4], WH1[4];
#pragma unroll
    for (int kk = 0; kk < 4; ++kk) {
      const float* wr0 = Wi2h + (size_t)(16 * (2 * wave + 0) + n16) * (IN_SZ + HID);
      const float* wr1 = Wi2h + (size_t)(16 * (2 * wave + 1) + n16) * (IN_SZ + HID);
      s16x8 a, b;
#pragma unroll
      for (int j = 0; j < 8; ++j) {
        a[j] = (short)f2bf(wr0[IN_SZ + 32 * kk + KOFF(g, j)]);
        b[j] = (short)f2bf(wr1[IN_SZ + 32 * kk + KOFF(g, j)]);
      }
      WH0[kk] = a; WH1[kk] = b;
    }

    // out-tiles: waves 0..2 -> {wave}; wave 3 -> {3, 4}
    const int nt = (wave == 3) ? 2 : 1;
    s16x8 wO[2][4];
    f32x4 bov[2];
    uint32_t ybase[2];
    int trow[2];
#pragma unroll
    for (int ot = 0; ot < 2; ++ot) {
      const int tk = (ot == 0) ? wave : 4;
      const bool tv = (ot < nt);
#pragma unroll
      for (int kk = 0; kk < 4; ++kk) {
        s16x8 a;
#pragma unroll
        for (int j = 0; j < 8; ++j) {
          int m = 16 * tk + n16;
          a[j] = (short)((tv && m < OUT_SZ)
                         ? f2bf(Wi2o[(size_t)m * HID + 32 * kk + KOFF(g, j)]) : 0);
        }
        wO[ot][kk] = a;
      }
#pragma unroll
      for (int r = 0; r < 4; ++r) {
        int m = 16 * tk + 4 * g + r;
        bov[ot][r] = (tv && m < OUT_SZ) ? bi2o[m] : 0.f;
      }
      ybase[ot] = (uint32_t)(16 * tk + 4 * g) * (uint32_t)SB + (uint32_t)(b0 + n16);
      trow[ot] = 16 * tk + 4 * g;
    }

    // stage h0 frag `wave` (rows 32w + KOFF(g,j) at clamped col)
    {
      union { s16x8 v; uint32_t d[4]; } u;
#pragma unroll
      for (int q = 0; q < 4; ++q) {
        int r0 = 32 * wave + KOFF(g, 2 * q);
        int r1 = 32 * wave + KOFF(g, 2 * q + 1);
        float h0 = hidden[(size_t)r0 * BATCH + cc] * mask[(size_t)r0 * BATCH + cc];
        float h1 = hidden[(size_t)r1 * BATCH + cc] * mask[(size_t)r1 * BATCH + cc];
        u.d[q] = pk2bf(h0, h1);
      }
      sH[0][wave][lane] = u.v;
    }
    frag_barrier();

#define CSTEP(K)                                                                \
  {                                                                             \
    const int t = t6 + (K);                                                     \
    const int P = (K) & 1;                                                      \
    f32x4 a = sA[P][2 * wave + 0][lane];   /* ax(t) incl. bias */               \
    f32x4 b = sA[P][2 * wave + 1][lane];                                        \
    s16x8 H0 = sH[P][0][lane], H1 = sH[P][1][lane];                             \
    s16x8 H2 = sH[P][2][lane], H3 = sH[P][3][lane];                             \
    f32x4 a2 = {0.f, 0.f, 0.f, 0.f}, b2 = {0.f, 0.f, 0.f, 0.f};                 \
    mfma16(a, WH0[0], H0);  mfma16(a2, WH0[1], H1);                             \
    mfma16(b, WH1[0], H0);  mfma16(b2, WH1[1], H1);                             \
    mfma16(a, WH0[2], H2);  mfma16(a2, WH0[3], H3);                             \
    mfma16(b, WH1[2], H2);  mfma16(b2, WH1[3], H3);                             \
    /* tanh + publish full frag `wave` (D-frag(2w,2w+1) == B-frag w) */         \
    {                                                                           \
      f32x4 s0 = a + a2, s1 = b + b2;                                           \
      union { s16x8 v; uint32_t d[4]; } u;                                      \
      u.d[0] = pk2bf(fast_tanh(s0[0]), fast_tanh(s0[1]));                       \
      u.d[1] = pk2bf(fast_tanh(s0[2]), fast_tanh(s0[3]));                       \
      u.d[2] = pk2bf(fast_tanh(s1[0]), fast_tanh(s1[1]));                       \
      u.d[3] = pk2bf(fast_tanh(s1[2]), fast_tanh(s1[3]));                       \
      sH[P ^ 1][wave][lane] = u.v;                                              \
    }                                                                           \
    /* i2o(t-1) on in-register H; stores fire-and-forget */                     \
    if (t > 0) {                                                                \
      const uint32_t ty = (uint32_t)(t - 1) * (uint32_t)BATCH;                  \
      _Pragma("unroll")                                                         \
      for (int ot = 0; ot < 2; ++ot) {                                          \
        if (ot < nt) {                                                          \
          f32x4 ao = bov[ot];                                                   \
          mfma16(ao, wO[ot][0], H0); mfma16(ao, wO[ot][1], H1);                 \
          mfma16(ao, wO[ot][2], H2); mfma16(ao, wO[ot][3], H3);                 \
          if (n16 < BT) {                                                       \
            _Pragma("unroll")                                                   \
            for (int r = 0; r < 4; ++r)                                         \
              if (trow[ot] + r < OUT_SZ)                                        \
                Y[(size_t)(ybase[ot] + (uint32_t)r * SB + ty)] = fmaxf(ao[r], 0.f); \
          }                                                                     \
        }                                                                       \
      }                                                                         \
    }                                                                           \
    frag_barrier();                                                             \
  }

    for (int t6 = 0; t6 < 510; t6 += 6) {
      CSTEP(0) CSTEP(1) CSTEP(2) CSTEP(3) CSTEP(4) CSTEP(5)
    }
    {
      const int t6 = 510;
      CSTEP(0) CSTEP(1)   // t = 510, 511
    }
#undef CSTEP

    // epilogue: y_511 from h_512 (t=511 published into sH[0])
    {
      s16x8 H0 = sH[0][0][lane], H1 = sH[0][1][lane];
      s16x8 H2 = sH[0][2][lane], H3 = sH[0][3][lane];
      const uint32_t ty = 511u * (uint32_t)BATCH;
#pragma unroll
      for (int ot = 0; ot < 2; ++ot) {
        if (ot < nt) {
          f32x4 ao = bov[ot];
          mfma16(ao, wO[ot][0], H0); mfma16(ao, wO[ot][1], H1);
          mfma16(ao, wO[ot][2], H2); mfma16(ao, wO[ot][3], H3);
          if (n16 < BT) {
#pragma unroll
            for (int r = 0; r < 4; ++r)
              if (trow[ot] + r < OUT_SZ)
                Y[(size_t)(ybase[ot] + (uint32_t)r * SB + ty)] = fmaxf(ao[r], 0.f);
          }
        }
      }
    }

  } else {
    // ====== SERVICE (2 waves): ax(t+1) = bi2h + Wx*x_{t+1}, one interval ahead ======
    const int sv = wave - 4;                 // 0..1 -> tiles 4sv..4sv+3
    const int tb = 4 * sv;

    // Wx A-frags for 4 tiles, k-tiles 0..3 (the x columns): 64 VGPR
    s16x8 Wx[4][4];
    f32x4 bhv4[4];
#pragma unroll
    for (int tt = 0; tt < 4; ++tt) {
      const float* wr = Wi2h + (size_t)(16 * (tb + tt) + n16) * (IN_SZ + HID);
#pragma unroll
      for (int kk = 0; kk < 4; ++kk) {
        s16x8 a;
#pragma unroll
        for (int j = 0; j < 8; ++j)
          a[j] = (short)f2bf(wr[32 * kk + KOFF(g, j)]);
        Wx[tt][kk] = a;
      }
#pragma unroll
      for (int r = 0; r < 4; ++r)
        bhv4[tt][r] = bi2h[16 * (tb + tt) + 4 * g + r];
    }

    // x addressing: raw q[8*kk + j] = x[row = 32kk + KOFF(g,j)][cc] at time T
    const char* const xB = (const char*)x;
    uint32_t xo[8];   // byte offset for kk=0 rows; add kk*KSTRIDE + T*4*BATCH
#pragma unroll
    for (int j = 0; j < 8; ++j)
      xo[j] = ((uint32_t)KOFF(g, j) * (uint32_t)SB + (uint32_t)cc) * 4u;
    const uint32_t KSTRIDE = 32u * (uint32_t)SB * 4u;

#define FILLQ(Q, T)                                                             \
    {                                                                           \
      const uint32_t to = (uint32_t)(T) * ((uint32_t)BATCH * 4u);               \
      _Pragma("unroll")                                                         \
      for (int kk = 0; kk < 4; ++kk)                                            \
        _Pragma("unroll")                                                       \
        for (int j = 0; j < 8; ++j)                                             \
          Q[8 * kk + j] = *(const float*)(xB + xo[j] + kk * KSTRIDE + to);      \
    }
#define AXCOMP(Q, DST)                                                          \
    {                                                                           \
      s16x8 X0, X1, X2, X3;                                                     \
      {                                                                         \
        union { s16x8 v; uint32_t d[4]; } u;                                    \
        _Pragma("unroll")                                                       \
        for (int q = 0; q < 4; ++q) u.d[q] = pk2bf(Q[2 * q], Q[2 * q + 1]);     \
        X0 = u.v;                                                               \
        _Pragma("unroll")                                                       \
        for (int q = 0; q < 4; ++q) u.d[q] = pk2bf(Q[8 + 2 * q], Q[9 + 2 * q]); \
        X1 = u.v;                                                               \
        _Pragma("unroll")                                                       \
        for (int q = 0; q < 4; ++q) u.d[q] = pk2bf(Q[16 + 2 * q], Q[17 + 2 * q]); \
        X2 = u.v;                                                               \
        _Pragma("unroll")                                                       \
        for (int q = 0; q < 4; ++q) u.d[q] = pk2bf(Q[24 + 2 * q], Q[25 + 2 * q]); \
        X3 = u.v;                                                               \
      }                                                                         \
      _Pragma("unroll")                                                         \
      for (int tt = 0; tt < 4; ++tt) {                                          \
        f32x4 ac = bhv4[tt];                                                    \
        mfma16(ac, Wx[tt][0], X0); mfma16(ac, Wx[tt][1], X1);                   \
        mfma16(ac, Wx[tt][2], X2); mfma16(ac, Wx[tt][3], X3);                   \
        sA[DST][tb + tt][lane] = ac;                                            \
      }                                                                         \
    }

    // prologue: ax(0) -> sA[0]; q0=x1, q1=x2, q2=x3
    float q0[32], q1[32], q2[32];
    FILLQ(q0, 0)
    AXCOMP(q0, 0)
    FILLQ(q0, 1) FILLQ(q1, 2) FILLQ(q2, 3)
    frag_barrier();

    // SSTEP(K): t=t6+K; consume q(K%3) = x(t+1) -> ax(t+1) -> sA[(t+1)&1];
    // reload q(K%3) = x(t+4)  (3-interval slack)
#define SSTEP(K, Q)                                                             \
  {                                                                             \
    const int t = t6 + (K);                                                     \
    AXCOMP(Q, ((K) & 1) ^ 1)                                                    \
    {                                                                           \
      const int tn = (t + 4 > 511) ? 511 : t + 4;                               \
      FILLQ(Q, tn)                                                              \
    }                                                                           \
    frag_barrier();                                                             \
  }

    for (int t6 = 0; t6 < 510; t6 += 6) {
      SSTEP(0, q0) SSTEP(1, q1) SSTEP(2, q2) SSTEP(3, q0) SSTEP(4, q1) SSTEP(5, q2)
    }
    {
      const int t6 = 510;
      SSTEP(0, q0) SSTEP(1, q1)   // t = 510, 511 -> barrier counts match compute
    }
#undef SSTEP
#undef AXCOMP
#undef FILLQ
  }
}

extern "C" void kernel_launch(void* const* d_in, const int* in_sizes, int n_in,
                              void* d_out, int out_size, void* d_ws, size_t ws_size,
                              hipStream_t stream) {
  const float* x      = (const float*)d_in[0];
  const float* hidden = (const float*)d_in[1];
  const float* mask   = (const float*)d_in[2];
  const float* Wi2h   = (const float*)d_in[3];
  const float* bi2h   = (const float*)d_in[4];
  const float* Wi2o   = (const float*)d_in[5];
  const float* bi2o   = (const float*)d_in[6];
  float* Y = (float*)d_out;
  (void)in_sizes; (void)n_in; (void)out_size; (void)d_ws; (void)ws_size;
  rnn_kernel<<<dim3(BATCH / BT), dim3(NTHR), 0, stream>>>(
      x, hidden, mask, Wi2h, bi2h, Wi2o, bi2o, Y);
}

// Round 19
// 431.835 us; speedup vs baseline: 1.4845x; 1.4845x over previous
//
#include <hip/hip_runtime.h>
#include <hip/hip_bf16.h>
#include <stdint.h>

#define IN_SZ 128
#define HID 128
#define OUT_SZ 67
#define SEQ 512
#define BATCH 2048
#define BT 8
#define NTHR 448   // 4 compute + 2 staging + 1 output wave
#define SB (SEQ * BATCH)   // 1048576

typedef __attribute__((ext_vector_type(4))) float f32x4;
typedef __attribute__((ext_vector_type(8))) short s16x8;
typedef __attribute__((ext_vector_type(8))) __bf16 bf16x8;

static __device__ __forceinline__ unsigned short f2bf(float f) {
  union { float f; uint32_t u; } c; c.f = f;
  uint32_t u = c.u;
  uint32_t r = u + 0x7FFFu + ((u >> 16) & 1u);
  return (unsigned short)(r >> 16);
}
static __device__ __forceinline__ uint32_t pk2bf(float lo, float hi) {
  __hip_bfloat162 h2 = __float22bfloat162_rn(float2{lo, hi});
  union { __hip_bfloat162 h; uint32_t u; } c; c.h = h2;
  return c.u;
}
static __device__ __forceinline__ float fast_tanh(float x) {
  float e = __builtin_amdgcn_exp2f(x * 2.885390081777927f);
  float r = __builtin_amdgcn_rcpf(e + 1.f);
  return __builtin_fmaf(-2.f, r, 1.f);
}
static __device__ __forceinline__ void mfma16(f32x4& c, s16x8 a, s16x8 b) {
  c = __builtin_amdgcn_mfma_f32_16x16x32_bf16(
        __builtin_bit_cast(bf16x8, a), __builtin_bit_cast(bf16x8, b), c, 0, 0, 0);
}
#define KOFF(g, j) (4 * (g) + ((j) & 3) + (((j) >> 2) << 4))

// clobber-free barrier (validated R9-R18): lgkm-only drain, vm ops float across
static __device__ __forceinline__ void frag_barrier() {
  __builtin_amdgcn_sched_barrier(0);
  asm volatile("s_waitcnt lgkmcnt(0)");
  __builtin_amdgcn_s_barrier();
  __builtin_amdgcn_sched_barrier(0);
}

__global__ __launch_bounds__(NTHR, 1) void rnn_kernel(
    const float* __restrict__ x, const float* __restrict__ hidden,
    const float* __restrict__ mask, const float* __restrict__ Wi2h,
    const float* __restrict__ bi2h, const float* __restrict__ Wi2o,
    const float* __restrict__ bi2o, float* __restrict__ Y) {

  __shared__ s16x8 sX[3][4][64];   // x frags, triple ring (staged 2 ahead); 12 KB
  __shared__ s16x8 sH[2][4][64];   // h frags, double buffer; 8 KB

  const int tid = threadIdx.x;
  const int wave = tid >> 6;      // 0..3 compute, 4..5 staging, 6 output
  const int lane = tid & 63;
  const int g = lane >> 4;
  const int n16 = lane & 15;
  const int bid = ((blockIdx.x & 7) << 5) | (blockIdx.x >> 3);  // XCD swizzle
  const int b0 = bid * BT;
  const int cc = (b0 + n16 < BATCH) ? (b0 + n16) : (BATCH - 1);

  if (wave < 4) {
    // ====== COMPUTE: i2h (2 tiles) + tanh + publish; no i2o, no VMEM ======
    s16x8 W0[8], W1[8];
#pragma unroll
    for (int kt = 0; kt < 8; ++kt) {
      const float* wr0 = Wi2h + (size_t)(16 * (2 * wave + 0) + n16) * (IN_SZ + HID);
      const float* wr1 = Wi2h + (size_t)(16 * (2 * wave + 1) + n16) * (IN_SZ + HID);
      s16x8 w8a, w8b;
#pragma unroll
      for (int j = 0; j < 8; ++j) {
        w8a[j] = (short)f2bf(wr0[32 * kt + KOFF(g, j)]);
        w8b[j] = (short)f2bf(wr1[32 * kt + KOFF(g, j)]);
      }
      W0[kt] = w8a; W1[kt] = w8b;
    }
    f32x4 bhv0, bhv1;
#pragma unroll
    for (int r = 0; r < 4; ++r) {
      bhv0[r] = bi2h[16 * (2 * wave + 0) + 4 * g + r];
      bhv1[r] = bi2h[16 * (2 * wave + 1) + 4 * g + r];
    }

    // stage h0 frag `wave` (rows 32w + KOFF(g,j), clamped col)
    {
      union { s16x8 v; uint32_t d[4]; } u;
#pragma unroll
      for (int q = 0; q < 4; ++q) {
        int r0 = 32 * wave + KOFF(g, 2 * q);
        int r1 = 32 * wave + KOFF(g, 2 * q + 1);
        float h0 = hidden[(size_t)r0 * BATCH + cc] * mask[(size_t)r0 * BATCH + cc];
        float h1 = hidden[(size_t)r1 * BATCH + cc] * mask[(size_t)r1 * BATCH + cc];
        u.d[q] = pk2bf(h0, h1);
      }
      sH[0][wave][lane] = u.v;
    }
    frag_barrier();

#define CSTEP(K)                                                                \
  {                                                                             \
    const int P = (K) & 1;                                                      \
    const int S = (K) % 3;                                                      \
    s16x8 X0 = sX[S][0][lane], X1 = sX[S][1][lane];                             \
    s16x8 X2 = sX[S][2][lane], X3 = sX[S][3][lane];                             \
    s16x8 H0 = sH[P][0][lane], H1 = sH[P][1][lane];                             \
    s16x8 H2 = sH[P][2][lane], H3 = sH[P][3][lane];                             \
    f32x4 a = bhv0, a2 = {0.f, 0.f, 0.f, 0.f};                                  \
    f32x4 b = bhv1, b2 = {0.f, 0.f, 0.f, 0.f};                                  \
    mfma16(a, W0[0], X0);  mfma16(a2, W0[1], X1);                               \
    mfma16(b, W1[0], X0);  mfma16(b2, W1[1], X1);                               \
    mfma16(a, W0[2], X2);  mfma16(a2, W0[3], X3);                               \
    mfma16(b, W1[2], X2);  mfma16(b2, W1[3], X3);                               \
    mfma16(a, W0[4], H0);  mfma16(a2, W0[5], H1);                               \
    mfma16(b, W1[4], H0);  mfma16(b2, W1[5], H1);                               \
    mfma16(a, W0[6], H2);  mfma16(a2, W0[7], H3);                               \
    mfma16(b, W1[6], H2);  mfma16(b2, W1[7], H3);                               \
    {                                                                           \
      f32x4 s0 = a + a2, s1 = b + b2;                                           \
      union { s16x8 v; uint32_t d[4]; } u;                                      \
      u.d[0] = pk2bf(fast_tanh(s0[0]), fast_tanh(s0[1]));                       \
      u.d[1] = pk2bf(fast_tanh(s0[2]), fast_tanh(s0[3]));                       \
      u.d[2] = pk2bf(fast_tanh(s1[0]), fast_tanh(s1[1]));                       \
      u.d[3] = pk2bf(fast_tanh(s1[2]), fast_tanh(s1[3]));                       \
      sH[P ^ 1][wave][lane] = u.v;                                              \
    }                                                                           \
    frag_barrier();                                                             \
  }

    for (int t6 = 0; t6 < 510; t6 += 6) {
      CSTEP(0) CSTEP(1) CSTEP(2) CSTEP(3) CSTEP(4) CSTEP(5)
    }
    CSTEP(0) CSTEP(1)   // t = 510, 511
#undef CSTEP

  } else if (wave < 6) {
    // ===== STAGING (2 waves): x load + stage into sX ring, 2 intervals ahead =====
    const int svl = ((wave - 4) << 6) | lane;   // 0..127
    const int rp = svl >> 1;
    const int R0 = 2 * rp;
    const int lcb = (svl & 1) * 4;
    const int skk = R0 >> 5;
    const int r5 = R0 & 31;
    const int sg = (r5 < 16) ? (r5 >> 2) : ((r5 - 16) >> 2);
    const int sq = ((r5 & 2) >> 1) + ((r5 < 16) ? 0 : 2);
    const int slb = sg << 4;
    const char* const xB = (const char*)x;
    const uint32_t xr0 = ((uint32_t)R0 * (uint32_t)SB + (uint32_t)b0) * 4u;
    const uint32_t xr1 = ((uint32_t)(R0 + 1) * (uint32_t)SB + (uint32_t)b0) * 4u;

#pragma unroll
    for (int tt = 0; tt < 2; ++tt) {
      const uint32_t to = (uint32_t)tt * (BATCH * 4u);
#pragma unroll
      for (int i = 0; i < 4; ++i) {
        const int lc = lcb + i;
        float v0 = *(const float*)(xB + xr0 + to + 4u * lc);
        float v1 = *(const float*)(xB + xr1 + to + 4u * lc);
        ((uint32_t*)&sX[tt][skk][slb | lc])[sq] = pk2bf(v0, v1);
      }
    }
    float q0[8], q1[8], q2[8], q3[8], q4[8], q5[8];
#define FILLQ(Q, T)                                                             \
    {                                                                           \
      const uint32_t to = (uint32_t)(T) * (BATCH * 4u);                         \
      _Pragma("unroll")                                                         \
      for (int i = 0; i < 4; ++i) {                                             \
        Q[2 * i]     = *(const float*)(xB + xr0 + to + 4u * (lcb + i));         \
        Q[2 * i + 1] = *(const float*)(xB + xr1 + to + 4u * (lcb + i));         \
      }                                                                         \
    }
    FILLQ(q0, 2) FILLQ(q1, 3) FILLQ(q2, 4) FILLQ(q3, 5) FILLQ(q4, 6) FILLQ(q5, 7)
    frag_barrier();

#define SSTEP(K, Q)                                                             \
  {                                                                             \
    const int t = t6 + (K);                                                     \
    const int SW = ((K) + 2) % 3;                                               \
    _Pragma("unroll")                                                           \
    for (int i = 0; i < 4; ++i) {                                               \
      const int lc = lcb + i;                                                   \
      ((uint32_t*)&sX[SW][skk][slb | lc])[sq] = pk2bf(Q[2 * i], Q[2 * i + 1]);  \
    }                                                                           \
    {                                                                           \
      const int tn = (t + 8 > 511) ? 511 : t + 8;                               \
      FILLQ(Q, tn)                                                              \
    }                                                                           \
    frag_barrier();                                                             \
  }

    for (int t6 = 0; t6 < 510; t6 += 6) {
      SSTEP(0, q0) SSTEP(1, q1) SSTEP(2, q2) SSTEP(3, q3) SSTEP(4, q4) SSTEP(5, q5)
    }
    {
      const int t6 = 510;
      SSTEP(0, q0) SSTEP(1, q1)   // t = 510, 511
    }
#undef SSTEP
#undef FILLQ

  } else {
    // ===== OUTPUT WAVE: all 5 out-tiles; i2o + Y stores; ZERO loads in loop =====
    s16x8 wO[5][4];
    f32x4 bov[5];
    uint32_t ybase[5];
    int trow[5];
#pragma unroll
    for (int ot = 0; ot < 5; ++ot) {
#pragma unroll
      for (int kk = 0; kk < 4; ++kk) {
        s16x8 a;
#pragma unroll
        for (int j = 0; j < 8; ++j) {
          int m = 16 * ot + n16;
          a[j] = (short)((m < OUT_SZ)
                         ? f2bf(Wi2o[(size_t)m * HID + 32 * kk + KOFF(g, j)]) : 0);
        }
        wO[ot][kk] = a;
      }
#pragma unroll
      for (int r = 0; r < 4; ++r) {
        int m = 16 * ot + 4 * g + r;
        bov[ot][r] = (m < OUT_SZ) ? bi2o[m] : 0.f;
      }
      ybase[ot] = (uint32_t)(16 * ot + 4 * g) * (uint32_t)SB + (uint32_t)(b0 + n16);
      trow[ot] = 16 * ot + 4 * g;
    }

    frag_barrier();   // prologue barrier
    frag_barrier();   // interval t = 0: nothing to output yet

    for (int t = 1; t < SEQ; ++t) {
      const int P = t & 1;
      s16x8 H0 = sH[P][0][lane], H1 = sH[P][1][lane];
      s16x8 H2 = sH[P][2][lane], H3 = sH[P][3][lane];
      const uint32_t ty = (uint32_t)(t - 1) * (uint32_t)BATCH;
#pragma unroll
      for (int ot = 0; ot < 5; ++ot) {
        f32x4 ao = bov[ot];
        mfma16(ao, wO[ot][0], H0); mfma16(ao, wO[ot][1], H1);
        mfma16(ao, wO[ot][2], H2); mfma16(ao, wO[ot][3], H3);
        if (n16 < BT) {
#pragma unroll
          for (int r = 0; r < 4; ++r)
            if (trow[ot] + r < OUT_SZ)
              Y[(size_t)(ybase[ot] + (uint32_t)r * SB + ty)] = fmaxf(ao[r], 0.f);
        }
      }
      frag_barrier();
    }
    // 1 + 1 + 511 = 513 barriers: matches compute/staging.
    // epilogue: y_511 from h_512 (published into sH[0] at t = 511)
    {
      s16x8 H0 = sH[0][0][lane], H1 = sH[0][1][lane];
      s16x8 H2 = sH[0][2][lane], H3 = sH[0][3][lane];
      const uint32_t ty = 511u * (uint32_t)BATCH;
#pragma unroll
      for (int ot = 0; ot < 5; ++ot) {
        f32x4 ao = bov[ot];
        mfma16(ao, wO[ot][0], H0); mfma16(ao, wO[ot][1], H1);
        mfma16(ao, wO[ot][2], H2); mfma16(ao, wO[ot][3], H3);
        if (n16 < BT) {
#pragma unroll
          for (int r = 0; r < 4; ++r)
            if (trow[ot] + r < OUT_SZ)
              Y[(size_t)(ybase[ot] + (uint32_t)r * SB + ty)] = fmaxf(ao[r], 0.f);
        }
      }
    }
  }
}

extern "C" void kernel_launch(void* const* d_in, const int* in_sizes, int n_in,
                              void* d_out, int out_size, void* d_ws, size_t ws_size,
                              hipStream_t stream) {
  const float* x      = (const float*)d_in[0];
  const float* hidden = (const float*)d_in[1];
  const float* mask   = (const float*)d_in[2];
  const float* Wi2h   = (const float*)d_in[3];
  const float* bi2h   = (const float*)d_in[4];
  const float* Wi2o   = (const float*)d_in[5];
  const float* bi2o   = (const float*)d_in[6];
  float* Y = (float*)d_out;
  (void)in_sizes; (void)n_in; (void)out_size; (void)d_ws; (void)ws_size;
  rnn_kernel<<<dim3(BATCH / BT), dim3(NTHR), 0, stream>>>(
      x, hidden, mask, Wi2h, bi2h, Wi2o, bi2o, Y);
}